// Round 5
// baseline (476.034 us; speedup 1.0000x reference)
//
#include <hip/hip_runtime.h>
#include <stdint.h>

// Problem constants (from reference setup_inputs)
#define N_NODES 50000
#define NE      400000
#define HDIM    128
#define MPAD    50048     // 391 * 128, zero-padded rows for clean GEMM tiling
#define TE      128       // edges per tile in fused kernel
#define NTILE   (NE / TE) // 3125 (exact: 400000 = 3125*128)
#define SCAN_BS 512
#define SCAN_NB 98        // 98*512 = 50176 >= 50001

typedef __attribute__((ext_vector_type(8))) short bf16x8;   // 8 bf16 in 4 VGPRs
typedef __attribute__((ext_vector_type(4))) float f32x4;

// f32 -> bf16, RTNE via bit ops. DO NOT use (__bf16) casts or
// __builtin_convertvector-to-bf16 here: rounds 2+3 showed that path lowers
// through a libcall/expansion that spills all live regs around each call
// (WRITE_SIZE 58 MB -> 433/1019 MB, VALUBusy 83% -> 35/18%).
__device__ __forceinline__ ushort f2b(float f) {
    uint32_t u = __float_as_uint(f);
    uint32_t r = (u + 0x7fffu + ((u >> 16) & 1u)) >> 16;   // RTNE
    return (ushort)r;
}
__device__ __forceinline__ float b2f(ushort s) {
    return __uint_as_float(((uint32_t)s) << 16);
}

// activations: approx rcp instead of precise f32 division (saves ~9 VALU/elem;
// v_rcp_f32 + v_exp_f32 are real instructions — no libcall risk)
__device__ __forceinline__ float silu_f(float x) {
    return x * __builtin_amdgcn_rcpf(1.f + __expf(-x));
}
__device__ __forceinline__ float tanh_f(float x) {
    return fmaf(-2.f, __builtin_amdgcn_rcpf(1.f + __expf(2.f * x)), 1.f);
}

// ---------------------------------------------------------------------------
// Fused: Xc[row,0:128]=bf16(x), Xc[row,128:256]=bf16(pe) (pad rows 0),
// and out baseline ONLY for non-covered nodes (boundary/deg-0); interior
// nodes are fully written by k_fused's direct-store path.
__global__ void k_prep_nodes(const float4* __restrict__ x, const float4* __restrict__ pe,
                             const int* __restrict__ cov,
                             ushort* __restrict__ Xc, float4* __restrict__ out) {
    int idx = blockIdx.x * 256 + threadIdx.x;
    int row = idx >> 6;
    int cq  = idx & 63;
    float4 v = make_float4(0.f, 0.f, 0.f, 0.f);
    if (row < N_NODES) {
        bool wr = (cov[row] == 0);
        if (cq < 32) { v = x[row * 32 + cq];          if (wr) out[row * 32 + cq] = v; }
        else         { v = pe[row * 32 + (cq - 32)];  if (wr) out[N_NODES * 32 + row * 32 + (cq - 32)] = v; }
    }
    ushort r[4] = { f2b(v.x), f2b(v.y), f2b(v.z), f2b(v.w) };
    *(uint2*)(Xc + (size_t)row * 256 + cq * 4) = *(const uint2*)r;
}

// Build transposed bf16 weights + dist-row extracts.
__global__ void k_prep_w(const float* __restrict__ W1, const float* __restrict__ Wp1,
                         const float* __restrict__ W2, const float* __restrict__ Wp2,
                         ushort* __restrict__ WcT, ushort* __restrict__ W2t,
                         ushort* __restrict__ Wp2t, float* __restrict__ w1d,
                         float* __restrict__ wp1d) {
    int b = blockIdx.x, t = threadIdx.x;
    if (b < 512) {
        int n = b, k = t;
        float v;
        if (n < 128)       v = W1[k * HDIM + n];
        else if (n < 256)  v = W1[(256 + k) * HDIM + (n - 128)];
        else if (n < 384)  v = (k < 128) ? 0.f : Wp1[(k - 128) * HDIM + (n - 256)];
        else               v = (k < 128) ? 0.f : Wp1[k * HDIM + (n - 384)];
        WcT[n * 256 + k] = f2b(v);
    } else if (b < 640) {
        if (t < 128) { int n = b - 512; W2t[n * HDIM + t] = f2b(W2[t * HDIM + n]); }
    } else if (b < 768) {
        if (t < 128) { int n = b - 640; Wp2t[n * HDIM + t] = f2b(Wp2[t * HDIM + n]); }
    } else {
        if (t < 128) w1d[t] = W1[512 * HDIM + t];
        else if (t < 256) wp1d[t - 128] = Wp1[256 * HDIM + (t - 128)];
    }
}

// ---------------------------------------------------------------------------
// Counting sort by receiver: hist -> 3-kernel multi-block scan -> place(+dist).
__global__ void k_hist(const int* __restrict__ eidx, int* __restrict__ cnt) {
    int e = blockIdx.x * 256 + threadIdx.x;
    if (e < NE) atomicAdd(&cnt[eidx[NE + e]], 1);
}

__global__ __launch_bounds__(SCAN_BS) void k_scan1(const int* __restrict__ cnt,
                                                   int* __restrict__ locs,
                                                   int* __restrict__ sums) {
    __shared__ int sh[SCAN_BS];
    int tid = threadIdx.x;
    int i = blockIdx.x * SCAN_BS + tid;
    int v = (i < N_NODES) ? cnt[i] : 0;
    sh[tid] = v;
    __syncthreads();
    for (int off = 1; off < SCAN_BS; off <<= 1) {
        int t = (tid >= off) ? sh[tid - off] : 0;
        __syncthreads();
        sh[tid] += t;
        __syncthreads();
    }
    locs[i] = sh[tid];                       // inclusive scan within block
    if (tid == SCAN_BS - 1) sums[blockIdx.x] = sh[tid];
}

__global__ void k_scan2(int* __restrict__ sums) {
    __shared__ int sh[128];
    int tid = threadIdx.x;
    sh[tid] = (tid < SCAN_NB) ? sums[tid] : 0;
    __syncthreads();
    for (int off = 1; off < 128; off <<= 1) {
        int t = (tid >= off) ? sh[tid - off] : 0;
        __syncthreads();
        sh[tid] += t;
        __syncthreads();
    }
    if (tid < SCAN_NB) sums[tid] = sh[tid];  // inclusive block sums
}

__global__ __launch_bounds__(SCAN_BS) void k_scan3(const int* __restrict__ cnt,
                                                   const int* __restrict__ locs,
                                                   const int* __restrict__ sums,
                                                   int* __restrict__ start,
                                                   int* __restrict__ cursor,
                                                   int* __restrict__ nodeCov) {
    int tid = threadIdx.x, b = blockIdx.x;
    int i = b * SCAN_BS + tid;
    if (i > N_NODES) return;
    int base = b ? sums[b - 1] : 0;
    int v = (i < N_NODES) ? cnt[i] : 0;
    int ex = base + locs[i] - v;             // exclusive prefix
    start[i] = ex;
    if (i < N_NODES) {
        cursor[i] = ex;
        // covered: all edges of node i live in one 128-edge tile ->
        // k_fused interior direct-store handles the full output row.
        int covered = (v > 0) && ((ex >> 7) == ((ex + v - 1) >> 7));
        nodeCov[i] = covered;
    }
}

// place edge into sorted slot; also extract send/rec/dist into sorted arrays
__global__ void k_place(const int* __restrict__ eidx, const float* __restrict__ pos,
                        int* __restrict__ cursor, int* __restrict__ sendS,
                        int* __restrict__ recS, float* __restrict__ distS) {
    int e = blockIdx.x * 256 + threadIdx.x;
    if (e >= NE) return;
    int s = eidx[e], r = eidx[NE + e];
    int p = atomicAdd(&cursor[r], 1);
    sendS[p] = s; recS[p] = r;
    float dx = pos[s * 3 + 0] - pos[r * 3 + 0];
    float dy = pos[s * 3 + 1] - pos[r * 3 + 1];
    float dz = pos[s * 3 + 2] - pos[r * 3 + 2];
    distS[p] = sqrtf(dx * dx + dy * dy + dz * dz);
}

// ---------------------------------------------------------------------------
// Per-tile segment metadata, computed ONCE (p-invariant): for each 128-edge
// tile, the receiver-run starts/lengths/interior flags packed as
//   word = r0 | (len-1)<<7 | interior<<14 | node<<16
__global__ __launch_bounds__(128) void k_segmeta(const int* __restrict__ recS,
                                                 const int* __restrict__ startA,
                                                 const int* __restrict__ cntA,
                                                 uint32_t* __restrict__ tileSegs,
                                                 int* __restrict__ segCnt) {
    __shared__ int sR[128];
    __shared__ int sFlag[128];
    __shared__ int sStart[129];
    int tid = threadIdx.x;
    int t0 = blockIdx.x * 128;
    sR[tid] = recS[t0 + tid];
    __syncthreads();
    int f = (tid == 0) || (sR[tid] != sR[tid - 1]);
    sFlag[tid] = f;
    __syncthreads();
    for (int off = 1; off < 128; off <<= 1) {
        int v = (tid >= off) ? sFlag[tid - off] : 0;
        __syncthreads();
        sFlag[tid] += v;
        __syncthreads();
    }
    int nSeg = sFlag[127];
    if (f) sStart[sFlag[tid] - 1] = tid;
    if (tid == 0) { sStart[nSeg] = 128; segCnt[blockIdx.x] = nSeg; }
    __syncthreads();
    if (f) {
        int seg = sFlag[tid] - 1;
        int r0 = tid;
        int len = sStart[seg + 1] - r0;
        int n = sR[r0];
        int g0 = t0 + r0;
        int st = startA[n];
        uint32_t interior = (g0 == st) && (g0 + len == st + cntA[n]);
        tileSegs[(size_t)blockIdx.x * 128 + seg] =
            (uint32_t)r0 | ((uint32_t)(len - 1) << 7) | (interior << 14) | ((uint32_t)n << 16);
    }
}

// ---------------------------------------------------------------------------
// Pn[MPAD,512] bf16 = Xc[MPAD,256] @ Wc[256,512], via WcT.
__global__ __launch_bounds__(256) void k_node_gemm(const ushort* __restrict__ Xc,
                                                   const ushort* __restrict__ WcT,
                                                   ushort* __restrict__ Pn) {
    const int m0 = blockIdx.y * 128;
    const int n0 = blockIdx.x * 128;
    const int wave = threadIdx.x >> 6;
    const int lane = threadIdx.x & 63;
    const int l15 = lane & 15, quad = lane >> 4;
    const int qr = (wave >> 1) * 64, qc = (wave & 1) * 64;

    f32x4 acc[4][4];
#pragma unroll
    for (int i = 0; i < 4; i++)
#pragma unroll
        for (int j = 0; j < 4; j++) acc[i][j] = (f32x4){0.f, 0.f, 0.f, 0.f};

#pragma unroll
    for (int s = 0; s < 8; s++) {
        const int k0 = s * 32 + quad * 8;
        bf16x8 a[4], b[4];
#pragma unroll
        for (int rg = 0; rg < 4; rg++) {
            int row = m0 + qr + rg * 16 + l15;
            a[rg] = *(const bf16x8*)(Xc + row * 256 + k0);
        }
#pragma unroll
        for (int cg = 0; cg < 4; cg++) {
            int nn = n0 + qc + cg * 16 + l15;
            b[cg] = *(const bf16x8*)(WcT + nn * 256 + k0);
        }
#pragma unroll
        for (int rg = 0; rg < 4; rg++)
#pragma unroll
            for (int cg = 0; cg < 4; cg++)
                acc[rg][cg] = __builtin_amdgcn_mfma_f32_16x16x32_bf16(a[rg], b[cg], acc[rg][cg], 0, 0, 0);
    }

#pragma unroll
    for (int rg = 0; rg < 4; rg++)
#pragma unroll
        for (int cg = 0; cg < 4; cg++) {
            int col = n0 + qc + cg * 16 + l15;
            int rowb = m0 + qr + rg * 16 + quad * 4;
#pragma unroll
            for (int r = 0; r < 4; r++)
                Pn[(size_t)(rowb + r) * 512 + col] = f2b(acc[rg][cg][r]);
        }
}

// ---------------------------------------------------------------------------
// FUSED edge pipeline: gather Pn rows -> layer-1 elementwise -> LDS (swizzled)
// -> layer-2 MFMA -> epilogue -> segment reduce (precomputed meta).
// blockIdx.x = tile, blockIdx.y = p (0: x-path/silu, 1: pe-path/tanh).
// LDS = exactly 32 KB (only the tile) -> 5 blocks/CU; edge meta is loaded
// per-thread into registers (int4/float4, coalescer merges the 16x
// same-address redundancy); segment words read directly from L2 in phase 4.
__global__ __launch_bounds__(256, 5) void k_fused(
    const ushort* __restrict__ Pn,
    const int* __restrict__ sendS, const int* __restrict__ recS,
    const float* __restrict__ distS,
    const uint32_t* __restrict__ tileSegs, const int* __restrict__ segCntA,
    const float* __restrict__ w1d, const float* __restrict__ wp1d,
    const float* __restrict__ b1, const float* __restrict__ bp1,
    const ushort* __restrict__ W2t, const ushort* __restrict__ Wp2t,
    const float* __restrict__ b2, const float* __restrict__ bp2,
    const float* __restrict__ x, const float* __restrict__ pe,
    float* __restrict__ out)
{
    __shared__ __align__(16) ushort sA[TE * 128];   // h1 tile (swizzled), then msg tile

    const int tid = threadIdx.x;
    const int tile = blockIdx.x;
    const int p = blockIdx.y;
    const int t0 = tile * TE;
    const int nSeg = segCntA[tile];

    const int g = tid >> 4, c = tid & 15;       // 16 col-groups x 16 threads; 8 edges/thread

    // edge meta straight to registers (8 consecutive edges per thread)
    const int e0 = t0 + g * 8;
    int4 sv0 = *(const int4*)(sendS + e0);
    int4 sv1 = *(const int4*)(sendS + e0 + 4);
    int4 rv0 = *(const int4*)(recS + e0);
    int4 rv1 = *(const int4*)(recS + e0 + 4);
    float4 dv0 = *(const float4*)(distS + e0);
    float4 dv1 = *(const float4*)(distS + e0 + 4);
    int se[8] = { sv0.x, sv0.y, sv0.z, sv0.w, sv1.x, sv1.y, sv1.z, sv1.w };
    int re[8] = { rv0.x, rv0.y, rv0.z, rv0.w, rv1.x, rv1.y, rv1.z, rv1.w };
    float de[8] = { dv0.x, dv0.y, dv0.z, dv0.w, dv1.x, dv1.y, dv1.z, dv1.w };

    const float* wd = p ? wp1d : w1d;
    const float* bb = p ? bp1 : b1;
    float4 wv0 = *(const float4*)(wd + c * 8);
    float4 wv1 = *(const float4*)(wd + c * 8 + 4);
    float4 bv0 = *(const float4*)(bb + c * 8);
    float4 bv1 = *(const float4*)(bb + c * 8 + 4);
    float wva[8] = { wv0.x, wv0.y, wv0.z, wv0.w, wv1.x, wv1.y, wv1.z, wv1.w };
    float bva[8] = { bv0.x, bv0.y, bv0.z, bv0.w, bv1.x, bv1.y, bv1.z, bv1.w };

    // phase 1: register gather from Pn (16 independent 16B loads) + layer-1
    {
        const ushort* PnS = Pn + p * 256 + c * 8;         // send-part cols
        const ushort* PnR = Pn + p * 256 + 128 + c * 8;   // rec-part cols
        uint4 us[8], ur[8];
#pragma unroll
        for (int e = 0; e < 8; e++) {
            us[e] = *(const uint4*)(PnS + (size_t)se[e] * 512);
            ur[e] = *(const uint4*)(PnR + (size_t)re[e] * 512);
        }
#define L1_BODY(ACT)                                                        \
        for (int e = 0; e < 8; e++) {                                       \
            int el = g * 8 + e;                                             \
            float d = de[e];                                                \
            const ushort* pus = (const ushort*)&us[e];                      \
            const ushort* pur = (const ushort*)&ur[e];                      \
            ushort res[8];                                                  \
            _Pragma("unroll")                                               \
            for (int j = 0; j < 8; j++) {                                   \
                float v = b2f(pus[j]) + b2f(pur[j]) + d * wva[j] + bva[j];  \
                res[j] = f2b(ACT(v));                                       \
            }                                                               \
            *(uint4*)(sA + el * 128 + ((c ^ (el & 15)) * 8)) = *(const uint4*)res; \
        }
        if (p) {
#pragma unroll
            L1_BODY(tanh_f)
        } else {
#pragma unroll
            L1_BODY(silu_f)
        }
#undef L1_BODY
    }
    __syncthreads();

    // phase 2: layer-2 MFMA; A from swizzled sA, B from global (L1-resident 32 KB)
    const int wave = tid >> 6, lane = tid & 63;
    const int l15 = lane & 15, quad = lane >> 4;
    const ushort* Wt = p ? Wp2t : W2t;

    f32x4 acc[2][8];
#pragma unroll
    for (int rg = 0; rg < 2; rg++)
#pragma unroll
        for (int cg = 0; cg < 8; cg++) acc[rg][cg] = (f32x4){0.f, 0.f, 0.f, 0.f};

#pragma unroll
    for (int s4 = 0; s4 < 4; s4++) {
        int cidx = s4 * 4 + quad;
        int row0 = wave * 32 + l15;                 // row & 15 == l15
        bf16x8 a0 = *(const bf16x8*)(sA + row0 * 128 + ((cidx ^ l15) * 8));
        bf16x8 a1 = *(const bf16x8*)(sA + (row0 + 16) * 128 + ((cidx ^ l15) * 8));
        int k0 = cidx * 8;
#pragma unroll
        for (int cg = 0; cg < 8; cg++) {
            bf16x8 b = *(const bf16x8*)(Wt + (cg * 16 + l15) * HDIM + k0);
            acc[0][cg] = __builtin_amdgcn_mfma_f32_16x16x32_bf16(a0, b, acc[0][cg], 0, 0, 0);
            acc[1][cg] = __builtin_amdgcn_mfma_f32_16x16x32_bf16(a1, b, acc[1][cg], 0, 0, 0);
        }
    }
    __syncthreads();   // all h1 reads done before msg overwrite

    // phase 3: bias + activation, msg tile into sA (plain layout)
    const float* bb2 = p ? bp2 : b2;
#define EPI_BODY(ACT)                                                       \
    for (int rg = 0; rg < 2; rg++) {                                        \
        int rowb = wave * 32 + rg * 16 + quad * 4;                          \
        _Pragma("unroll")                                                   \
        for (int cg = 0; cg < 8; cg++) {                                    \
            int col = cg * 16 + l15;                                        \
            float bias = bb2[col];                                          \
            _Pragma("unroll")                                               \
            for (int r = 0; r < 4; r++) {                                   \
                float v = acc[rg][cg][r] + bias;                            \
                sA[(rowb + r) * 128 + col] = f2b(ACT(v));                   \
            }                                                               \
        }                                                                   \
    }
    if (p) {
#pragma unroll
        EPI_BODY(tanh_f)
    } else {
#pragma unroll
        EPI_BODY(silu_f)
    }
#undef EPI_BODY
    __syncthreads();

    // phase 4: segment reduce + store/atomic; seg words direct from L2
    const float* basep = p ? pe : x;
    float* outb = out + (size_t)p * N_NODES * HDIM;
    const uint32_t* segp = tileSegs + (size_t)tile * TE;
    for (int task = tid; task < nSeg * 64; task += 256) {
        int seg = task >> 6, cp = task & 63;
        uint32_t wseg = segp[seg];                  // wave-uniform -> broadcast
        int r0  = wseg & 127;
        int len = ((wseg >> 7) & 127) + 1;
        int n   = wseg >> 16;
        float a0 = 0.f, a1 = 0.f;
        for (int rr = r0; rr < r0 + len; rr++) {
            unsigned int u = *(const unsigned int*)&sA[rr * 128 + cp * 2];
            a0 += b2f((ushort)(u & 0xffffu));
            a1 += b2f((ushort)(u >> 16));
        }
        float* op = outb + (size_t)n * HDIM + cp * 2;
        if ((wseg >> 14) & 1) {                     // interior: direct store
            float2 bv = *(const float2*)(basep + (size_t)n * HDIM + cp * 2);
            *(float2*)op = make_float2(bv.x + a0, bv.y + a1);
        } else {                                    // boundary: atomic
            atomicAdd(op, a0);
            atomicAdd(op + 1, a1);
        }
    }
}

// ---------------------------------------------------------------------------
extern "C" void kernel_launch(void* const* d_in, const int* in_sizes, int n_in,
                              void* d_out, int out_size, void* d_ws, size_t ws_size,
                              hipStream_t stream) {
    const float* x   = (const float*)d_in[0];
    const float* pos = (const float*)d_in[1];
    const float* pe  = (const float*)d_in[2];
    const int* eidx  = (const int*)d_in[3];
    const float* W1  = (const float*)d_in[4];
    const float* b1  = (const float*)d_in[5];
    const float* W2  = (const float*)d_in[6];
    const float* b2  = (const float*)d_in[7];
    const float* Wp1 = (const float*)d_in[8];
    const float* bp1 = (const float*)d_in[9];
    const float* Wp2 = (const float*)d_in[10];
    const float* bp2 = (const float*)d_in[11];
    float* out = (float*)d_out;

    // workspace carve-up
    char* w = (char*)d_ws;
    size_t off = 0;
    ushort* Xc   = (ushort*)(w + off); off += (size_t)MPAD * 256 * 2;   // 25.6 MB
    ushort* Pn   = (ushort*)(w + off); off += (size_t)MPAD * 512 * 2;   // 51.2 MB
    ushort* WcT  = (ushort*)(w + off); off += 512 * 256 * 2;
    ushort* W2t  = (ushort*)(w + off); off += 32768;
    ushort* Wp2t = (ushort*)(w + off); off += 32768;
    float*  w1d  = (float*)(w + off);  off += 2048;
    float*  wp1d = (float*)(w + off);  off += 2048;
    int* cnt     = (int*)(w + off);    off += 200704;                   // 50176*4
    int* startA  = (int*)(w + off);    off += 200704;
    int* cursor  = (int*)(w + off);    off += 200704;
    int* locs    = (int*)(w + off);    off += 200704;
    int* sums    = (int*)(w + off);    off += 512;
    int* sendS   = (int*)(w + off);    off += (size_t)NE * 4;
    int* recS    = (int*)(w + off);    off += (size_t)NE * 4;
    float* distS = (float*)(w + off);  off += (size_t)NE * 4;
    uint32_t* tileSegs = (uint32_t*)(w + off); off += (size_t)NTILE * 128 * 4;  // 1.6 MB
    int* segCntA = (int*)(w + off);    off += (size_t)NTILE * 4;
    int* nodeCov = (int*)(w + off);    off += 200704;

    // sort edges by receiver (+ dist/send/rec extraction)
    hipMemsetAsync(cnt, 0, (N_NODES + 1) * sizeof(int), stream);
    k_hist<<<(NE + 255) / 256, 256, 0, stream>>>(eidx, cnt);
    k_scan1<<<SCAN_NB, SCAN_BS, 0, stream>>>(cnt, locs, sums);
    k_scan2<<<1, 128, 0, stream>>>(sums);
    k_scan3<<<SCAN_NB, SCAN_BS, 0, stream>>>(cnt, locs, sums, startA, cursor, nodeCov);
    k_place<<<(NE + 255) / 256, 256, 0, stream>>>(eidx, pos, cursor, sendS, recS, distS);
    k_segmeta<<<NTILE, 128, 0, stream>>>(recS, startA, cnt, tileSegs, segCntA);

    // prep (fused Xc build + out baseline init for non-covered nodes only)
    k_prep_w<<<769, 256, 0, stream>>>(W1, Wp1, W2, Wp2, WcT, W2t, Wp2t, w1d, wp1d);
    k_prep_nodes<<<MPAD / 4, 256, 0, stream>>>((const float4*)x, (const float4*)pe,
                                               nodeCov, Xc, (float4*)out);

    // node-level GEMM: Pn = Xc @ Wc
    dim3 ggrid(4, MPAD / 128);
    k_node_gemm<<<ggrid, 256, 0, stream>>>(Xc, WcT, Pn);

    // fused edge pipeline: gather + layer1 + layer2 + segment reduce, both p paths
    dim3 fgrid(NTILE, 2);
    k_fused<<<fgrid, 256, 0, stream>>>(Pn, sendS, recS, distS, tileSegs, segCntA,
                                       w1d, wp1d, b1, bp1, W2t, Wp2t, b2, bp2,
                                       x, pe, out);
}

// Round 6
// 383.328 us; speedup vs baseline: 1.2418x; 1.2418x over previous
//
#include <hip/hip_runtime.h>
#include <stdint.h>

// Problem constants (from reference setup_inputs)
#define N_NODES 50000
#define NE      400000
#define HDIM    128
#define MPAD    50048     // 391 * 128, zero-padded rows for clean GEMM tiling
#define TE      128       // edges per tile in fused kernel
#define NTILE   (NE / TE) // 3125 (exact: 400000 = 3125*128)
#define SCAN_BS 512
#define SCAN_NB 98        // 98*512 = 50176 >= 50001

typedef __attribute__((ext_vector_type(8))) short bf16x8;   // 8 bf16 in 4 VGPRs
typedef __attribute__((ext_vector_type(4))) float f32x4;

// f32 -> bf16, RTNE via bit ops (prep/cold paths). DO NOT use (__bf16) casts:
// rounds 2+3 showed that path lowers through a libcall that spills all live
// regs around each call (WRITE_SIZE 58 MB -> 433/1019 MB).
__device__ __forceinline__ ushort f2b(float f) {
    uint32_t u = __float_as_uint(f);
    uint32_t r = (u + 0x7fffu + ((u >> 16) & 1u)) >> 16;   // RTNE
    return (ushort)r;
}
__device__ __forceinline__ float b2f(ushort s) {
    return __uint_as_float(((uint32_t)s) << 16);
}
// hot-path pair convert: single v_cvt_pk_bf16_f32 (RTNE), inline asm
// (real gfx950 instruction; avoids the libcall the (__bf16) cast takes).
// dst.lo = bf16(lo), dst.hi = bf16(hi).
__device__ __forceinline__ uint32_t cvtpk(float lo, float hi) {
    uint32_t r;
    asm("v_cvt_pk_bf16_f32 %0, %1, %2" : "=v"(r) : "v"(lo), "v"(hi));
    return r;
}

// activations: approx rcp instead of precise f32 division (saves ~9 VALU/elem;
// v_rcp_f32 + v_exp_f32 are real instructions — no libcall risk)
__device__ __forceinline__ float silu_f(float x) {
    return x * __builtin_amdgcn_rcpf(1.f + __expf(-x));
}
__device__ __forceinline__ float tanh_f(float x) {
    return fmaf(-2.f, __builtin_amdgcn_rcpf(1.f + __expf(2.f * x)), 1.f);
}

// ---------------------------------------------------------------------------
// Fused: Xc[row,0:128]=bf16(x), Xc[row,128:256]=bf16(pe) (pad rows 0),
// and out baseline ONLY for non-covered nodes (boundary/deg-0); interior
// nodes are fully written by k_fused's direct-store path.
__global__ void k_prep_nodes(const float4* __restrict__ x, const float4* __restrict__ pe,
                             const int* __restrict__ cov,
                             ushort* __restrict__ Xc, float4* __restrict__ out) {
    int idx = blockIdx.x * 256 + threadIdx.x;
    int row = idx >> 6;
    int cq  = idx & 63;
    float4 v = make_float4(0.f, 0.f, 0.f, 0.f);
    if (row < N_NODES) {
        bool wr = (cov[row] == 0);
        if (cq < 32) { v = x[row * 32 + cq];          if (wr) out[row * 32 + cq] = v; }
        else         { v = pe[row * 32 + (cq - 32)];  if (wr) out[N_NODES * 32 + row * 32 + (cq - 32)] = v; }
    }
    ushort r[4] = { f2b(v.x), f2b(v.y), f2b(v.z), f2b(v.w) };
    *(uint2*)(Xc + (size_t)row * 256 + cq * 4) = *(const uint2*)r;
}

// Build transposed bf16 weights + dist-row extracts.
__global__ void k_prep_w(const float* __restrict__ W1, const float* __restrict__ Wp1,
                         const float* __restrict__ W2, const float* __restrict__ Wp2,
                         ushort* __restrict__ WcT, ushort* __restrict__ W2t,
                         ushort* __restrict__ Wp2t, float* __restrict__ w1d,
                         float* __restrict__ wp1d) {
    int b = blockIdx.x, t = threadIdx.x;
    if (b < 512) {
        int n = b, k = t;
        float v;
        if (n < 128)       v = W1[k * HDIM + n];
        else if (n < 256)  v = W1[(256 + k) * HDIM + (n - 128)];
        else if (n < 384)  v = (k < 128) ? 0.f : Wp1[(k - 128) * HDIM + (n - 256)];
        else               v = (k < 128) ? 0.f : Wp1[k * HDIM + (n - 384)];
        WcT[n * 256 + k] = f2b(v);
    } else if (b < 640) {
        if (t < 128) { int n = b - 512; W2t[n * HDIM + t] = f2b(W2[t * HDIM + n]); }
    } else if (b < 768) {
        if (t < 128) { int n = b - 640; Wp2t[n * HDIM + t] = f2b(Wp2[t * HDIM + n]); }
    } else {
        if (t < 128) w1d[t] = W1[512 * HDIM + t];
        else if (t < 256) wp1d[t - 128] = Wp1[256 * HDIM + (t - 128)];
    }
}

// ---------------------------------------------------------------------------
// Counting sort by receiver: hist -> 3-kernel multi-block scan -> place(+dist).
__global__ void k_hist(const int* __restrict__ eidx, int* __restrict__ cnt) {
    int e = blockIdx.x * 256 + threadIdx.x;
    if (e < NE) atomicAdd(&cnt[eidx[NE + e]], 1);
}

__global__ __launch_bounds__(SCAN_BS) void k_scan1(const int* __restrict__ cnt,
                                                   int* __restrict__ locs,
                                                   int* __restrict__ sums) {
    __shared__ int sh[SCAN_BS];
    int tid = threadIdx.x;
    int i = blockIdx.x * SCAN_BS + tid;
    int v = (i < N_NODES) ? cnt[i] : 0;
    sh[tid] = v;
    __syncthreads();
    for (int off = 1; off < SCAN_BS; off <<= 1) {
        int t = (tid >= off) ? sh[tid - off] : 0;
        __syncthreads();
        sh[tid] += t;
        __syncthreads();
    }
    locs[i] = sh[tid];                       // inclusive scan within block
    if (tid == SCAN_BS - 1) sums[blockIdx.x] = sh[tid];
}

__global__ void k_scan2(int* __restrict__ sums) {
    __shared__ int sh[128];
    int tid = threadIdx.x;
    sh[tid] = (tid < SCAN_NB) ? sums[tid] : 0;
    __syncthreads();
    for (int off = 1; off < 128; off <<= 1) {
        int t = (tid >= off) ? sh[tid - off] : 0;
        __syncthreads();
        sh[tid] += t;
        __syncthreads();
    }
    if (tid < SCAN_NB) sums[tid] = sh[tid];  // inclusive block sums
}

__global__ __launch_bounds__(SCAN_BS) void k_scan3(const int* __restrict__ cnt,
                                                   const int* __restrict__ locs,
                                                   const int* __restrict__ sums,
                                                   int* __restrict__ start,
                                                   int* __restrict__ cursor,
                                                   int* __restrict__ nodeCov) {
    int tid = threadIdx.x, b = blockIdx.x;
    int i = b * SCAN_BS + tid;
    if (i > N_NODES) return;
    int base = b ? sums[b - 1] : 0;
    int v = (i < N_NODES) ? cnt[i] : 0;
    int ex = base + locs[i] - v;             // exclusive prefix
    start[i] = ex;
    if (i < N_NODES) {
        cursor[i] = ex;
        // covered: all edges of node i live in one 128-edge tile ->
        // k_fused interior direct-store handles the full output row.
        int covered = (v > 0) && ((ex >> 7) == ((ex + v - 1) >> 7));
        nodeCov[i] = covered;
    }
}

// place edge into sorted slot; also extract send/rec/dist into sorted arrays
__global__ void k_place(const int* __restrict__ eidx, const float* __restrict__ pos,
                        int* __restrict__ cursor, int* __restrict__ sendS,
                        int* __restrict__ recS, float* __restrict__ distS) {
    int e = blockIdx.x * 256 + threadIdx.x;
    if (e >= NE) return;
    int s = eidx[e], r = eidx[NE + e];
    int p = atomicAdd(&cursor[r], 1);
    sendS[p] = s; recS[p] = r;
    float dx = pos[s * 3 + 0] - pos[r * 3 + 0];
    float dy = pos[s * 3 + 1] - pos[r * 3 + 1];
    float dz = pos[s * 3 + 2] - pos[r * 3 + 2];
    distS[p] = sqrtf(dx * dx + dy * dy + dz * dz);
}

// ---------------------------------------------------------------------------
// Per-tile segment metadata, computed ONCE (p-invariant): for each 128-edge
// tile, the receiver-run starts/lengths/interior flags packed as
//   word = r0 | (len-1)<<7 | interior<<14 | node<<16
__global__ __launch_bounds__(128) void k_segmeta(const int* __restrict__ recS,
                                                 const int* __restrict__ startA,
                                                 const int* __restrict__ cntA,
                                                 uint32_t* __restrict__ tileSegs,
                                                 int* __restrict__ segCnt) {
    __shared__ int sR[128];
    __shared__ int sFlag[128];
    __shared__ int sStart[129];
    int tid = threadIdx.x;
    int t0 = blockIdx.x * 128;
    sR[tid] = recS[t0 + tid];
    __syncthreads();
    int f = (tid == 0) || (sR[tid] != sR[tid - 1]);
    sFlag[tid] = f;
    __syncthreads();
    for (int off = 1; off < 128; off <<= 1) {
        int v = (tid >= off) ? sFlag[tid - off] : 0;
        __syncthreads();
        sFlag[tid] += v;
        __syncthreads();
    }
    int nSeg = sFlag[127];
    if (f) sStart[sFlag[tid] - 1] = tid;
    if (tid == 0) { sStart[nSeg] = 128; segCnt[blockIdx.x] = nSeg; }
    __syncthreads();
    if (f) {
        int seg = sFlag[tid] - 1;
        int r0 = tid;
        int len = sStart[seg + 1] - r0;
        int n = sR[r0];
        int g0 = t0 + r0;
        int st = startA[n];
        uint32_t interior = (g0 == st) && (g0 + len == st + cntA[n]);
        tileSegs[(size_t)blockIdx.x * 128 + seg] =
            (uint32_t)r0 | ((uint32_t)(len - 1) << 7) | (interior << 14) | ((uint32_t)n << 16);
    }
}

// ---------------------------------------------------------------------------
// Pn[MPAD,512] bf16 = Xc[MPAD,256] @ Wc[256,512], via WcT.
__global__ __launch_bounds__(256) void k_node_gemm(const ushort* __restrict__ Xc,
                                                   const ushort* __restrict__ WcT,
                                                   ushort* __restrict__ Pn) {
    const int m0 = blockIdx.y * 128;
    const int n0 = blockIdx.x * 128;
    const int wave = threadIdx.x >> 6;
    const int lane = threadIdx.x & 63;
    const int l15 = lane & 15, quad = lane >> 4;
    const int qr = (wave >> 1) * 64, qc = (wave & 1) * 64;

    f32x4 acc[4][4];
#pragma unroll
    for (int i = 0; i < 4; i++)
#pragma unroll
        for (int j = 0; j < 4; j++) acc[i][j] = (f32x4){0.f, 0.f, 0.f, 0.f};

#pragma unroll
    for (int s = 0; s < 8; s++) {
        const int k0 = s * 32 + quad * 8;
        bf16x8 a[4], b[4];
#pragma unroll
        for (int rg = 0; rg < 4; rg++) {
            int row = m0 + qr + rg * 16 + l15;
            a[rg] = *(const bf16x8*)(Xc + row * 256 + k0);
        }
#pragma unroll
        for (int cg = 0; cg < 4; cg++) {
            int nn = n0 + qc + cg * 16 + l15;
            b[cg] = *(const bf16x8*)(WcT + nn * 256 + k0);
        }
#pragma unroll
        for (int rg = 0; rg < 4; rg++)
#pragma unroll
            for (int cg = 0; cg < 4; cg++)
                acc[rg][cg] = __builtin_amdgcn_mfma_f32_16x16x32_bf16(a[rg], b[cg], acc[rg][cg], 0, 0, 0);
    }

#pragma unroll
    for (int rg = 0; rg < 4; rg++)
#pragma unroll
        for (int cg = 0; cg < 4; cg++) {
            int col = n0 + qc + cg * 16 + l15;
            int rowb = m0 + qr + rg * 16 + quad * 4;
            uint32_t p01 = cvtpk(acc[rg][cg][0], acc[rg][cg][1]);
            uint32_t p23 = cvtpk(acc[rg][cg][2], acc[rg][cg][3]);
            Pn[(size_t)(rowb + 0) * 512 + col] = (ushort)p01;
            Pn[(size_t)(rowb + 1) * 512 + col] = (ushort)(p01 >> 16);
            Pn[(size_t)(rowb + 2) * 512 + col] = (ushort)p23;
            Pn[(size_t)(rowb + 3) * 512 + col] = (ushort)(p23 >> 16);
        }
}

// ---------------------------------------------------------------------------
// FUSED edge pipeline: gather Pn rows -> layer-1 elementwise -> LDS (swizzled)
// -> layer-2 MFMA -> epilogue -> segment reduce (precomputed meta).
// blockIdx.x = tile, blockIdx.y = p (0: x-path/silu, 1: pe-path/tanh).
// Structure = round-4 verified (LDS meta, lb(256,4), 64 VGPR, no spill);
// only change: f32->bf16 pair conversion via v_cvt_pk_bf16_f32.
__global__ __launch_bounds__(256, 4) void k_fused(
    const ushort* __restrict__ Pn,
    const int* __restrict__ sendS, const int* __restrict__ recS,
    const float* __restrict__ distS,
    const uint32_t* __restrict__ tileSegs, const int* __restrict__ segCntA,
    const float* __restrict__ w1d, const float* __restrict__ wp1d,
    const float* __restrict__ b1, const float* __restrict__ bp1,
    const ushort* __restrict__ W2t, const ushort* __restrict__ Wp2t,
    const float* __restrict__ b2, const float* __restrict__ bp2,
    const float* __restrict__ x, const float* __restrict__ pe,
    float* __restrict__ out)
{
    __shared__ __align__(16) ushort sA[TE * 128];   // h1 tile (swizzled), then msg tile
    __shared__ int sS[TE];
    __shared__ int sR[TE];
    __shared__ float sD[TE];
    __shared__ uint32_t sSeg[TE];

    const int tid = threadIdx.x;
    const int tile = blockIdx.x;
    const int p = blockIdx.y;
    const int t0 = tile * TE;

    // phase 0: stage sorted-edge meta + precomputed segments
    if (tid < TE) {
        sS[tid] = sendS[t0 + tid];
        sR[tid] = recS[t0 + tid];
        sD[tid] = distS[t0 + tid];
    } else {
        sSeg[tid - TE] = tileSegs[(size_t)tile * TE + (tid - TE)];
    }
    const int nSeg = segCntA[tile];

    const int g = tid >> 4, c = tid & 15;       // 16 col-groups x 16 threads; 8 edges/thread
    const float* wd = p ? wp1d : w1d;
    const float* bb = p ? bp1 : b1;
    float4 wv0 = *(const float4*)(wd + c * 8);
    float4 wv1 = *(const float4*)(wd + c * 8 + 4);
    float4 bv0 = *(const float4*)(bb + c * 8);
    float4 bv1 = *(const float4*)(bb + c * 8 + 4);
    float wva[8] = { wv0.x, wv0.y, wv0.z, wv0.w, wv1.x, wv1.y, wv1.z, wv1.w };
    float bva[8] = { bv0.x, bv0.y, bv0.z, bv0.w, bv1.x, bv1.y, bv1.z, bv1.w };
    __syncthreads();

    // phase 1: register gather from Pn (16 independent 16B loads) + layer-1
    {
        const ushort* PnS = Pn + p * 256 + c * 8;         // send-part cols
        const ushort* PnR = Pn + p * 256 + 128 + c * 8;   // rec-part cols
        uint4 us[8], ur[8];
#pragma unroll
        for (int e = 0; e < 8; e++) {
            int el = g * 8 + e;
            us[e] = *(const uint4*)(PnS + (size_t)sS[el] * 512);
            ur[e] = *(const uint4*)(PnR + (size_t)sR[el] * 512);
        }
#define L1_BODY(ACT)                                                        \
        for (int e = 0; e < 8; e++) {                                       \
            int el = g * 8 + e;                                             \
            float d = sD[el];                                               \
            const ushort* pus = (const ushort*)&us[e];                      \
            const ushort* pur = (const ushort*)&ur[e];                      \
            float vv[8];                                                    \
            _Pragma("unroll")                                               \
            for (int j = 0; j < 8; j++) {                                   \
                float v = b2f(pus[j]) + b2f(pur[j]) + d * wva[j] + bva[j];  \
                vv[j] = ACT(v);                                             \
            }                                                               \
            uint4 res;                                                      \
            res.x = cvtpk(vv[0], vv[1]);                                    \
            res.y = cvtpk(vv[2], vv[3]);                                    \
            res.z = cvtpk(vv[4], vv[5]);                                    \
            res.w = cvtpk(vv[6], vv[7]);                                    \
            *(uint4*)(sA + el * 128 + ((c ^ (el & 15)) * 8)) = res;         \
        }
        if (p) {
#pragma unroll
            L1_BODY(tanh_f)
        } else {
#pragma unroll
            L1_BODY(silu_f)
        }
#undef L1_BODY
    }
    __syncthreads();

    // phase 2: layer-2 MFMA; A from swizzled sA, B from global (L1-resident 32 KB)
    const int wave = tid >> 6, lane = tid & 63;
    const int l15 = lane & 15, quad = lane >> 4;
    const ushort* Wt = p ? Wp2t : W2t;

    f32x4 acc[2][8];
#pragma unroll
    for (int rg = 0; rg < 2; rg++)
#pragma unroll
        for (int cg = 0; cg < 8; cg++) acc[rg][cg] = (f32x4){0.f, 0.f, 0.f, 0.f};

#pragma unroll
    for (int s4 = 0; s4 < 4; s4++) {
        int cidx = s4 * 4 + quad;
        int row0 = wave * 32 + l15;                 // row & 15 == l15
        bf16x8 a0 = *(const bf16x8*)(sA + row0 * 128 + ((cidx ^ l15) * 8));
        bf16x8 a1 = *(const bf16x8*)(sA + (row0 + 16) * 128 + ((cidx ^ l15) * 8));
        int k0 = cidx * 8;
#pragma unroll
        for (int cg = 0; cg < 8; cg++) {
            bf16x8 b = *(const bf16x8*)(Wt + (cg * 16 + l15) * HDIM + k0);
            acc[0][cg] = __builtin_amdgcn_mfma_f32_16x16x32_bf16(a0, b, acc[0][cg], 0, 0, 0);
            acc[1][cg] = __builtin_amdgcn_mfma_f32_16x16x32_bf16(a1, b, acc[1][cg], 0, 0, 0);
        }
    }
    __syncthreads();   // all h1 reads done before msg overwrite

    // phase 3: bias + activation, msg tile into sA (plain layout)
    const float* bb2 = p ? bp2 : b2;
#define EPI_BODY(ACT)                                                       \
    for (int rg = 0; rg < 2; rg++) {                                        \
        int rowb = wave * 32 + rg * 16 + quad * 4;                          \
        _Pragma("unroll")                                                   \
        for (int cg = 0; cg < 8; cg++) {                                    \
            int col = cg * 16 + l15;                                        \
            float bias = bb2[col];                                          \
            float e0 = ACT(acc[rg][cg][0] + bias);                          \
            float e1 = ACT(acc[rg][cg][1] + bias);                          \
            float e2 = ACT(acc[rg][cg][2] + bias);                          \
            float e3 = ACT(acc[rg][cg][3] + bias);                          \
            uint32_t p01 = cvtpk(e0, e1);                                   \
            uint32_t p23 = cvtpk(e2, e3);                                   \
            sA[(rowb + 0) * 128 + col] = (ushort)p01;                       \
            sA[(rowb + 1) * 128 + col] = (ushort)(p01 >> 16);               \
            sA[(rowb + 2) * 128 + col] = (ushort)p23;                       \
            sA[(rowb + 3) * 128 + col] = (ushort)(p23 >> 16);               \
        }                                                                   \
    }
    if (p) {
#pragma unroll
        EPI_BODY(tanh_f)
    } else {
#pragma unroll
        EPI_BODY(silu_f)
    }
#undef EPI_BODY
    __syncthreads();

    // phase 4: segment reduce + store/atomic using precomputed meta
    const float* basep = p ? pe : x;
    float* outb = out + (size_t)p * N_NODES * HDIM;
    for (int task = tid; task < nSeg * 64; task += 256) {
        int seg = task >> 6, cp = task & 63;
        uint32_t wseg = sSeg[seg];
        int r0  = wseg & 127;
        int len = ((wseg >> 7) & 127) + 1;
        int n   = wseg >> 16;
        float a0 = 0.f, a1 = 0.f;
        for (int rr = r0; rr < r0 + len; rr++) {
            unsigned int u = *(const unsigned int*)&sA[rr * 128 + cp * 2];
            a0 += b2f((ushort)(u & 0xffffu));
            a1 += b2f((ushort)(u >> 16));
        }
        float* op = outb + (size_t)n * HDIM + cp * 2;
        if ((wseg >> 14) & 1) {                     // interior: direct store
            float2 bv = *(const float2*)(basep + (size_t)n * HDIM + cp * 2);
            *(float2*)op = make_float2(bv.x + a0, bv.y + a1);
        } else {                                    // boundary: atomic
            atomicAdd(op, a0);
            atomicAdd(op + 1, a1);
        }
    }
}

// ---------------------------------------------------------------------------
extern "C" void kernel_launch(void* const* d_in, const int* in_sizes, int n_in,
                              void* d_out, int out_size, void* d_ws, size_t ws_size,
                              hipStream_t stream) {
    const float* x   = (const float*)d_in[0];
    const float* pos = (const float*)d_in[1];
    const float* pe  = (const float*)d_in[2];
    const int* eidx  = (const int*)d_in[3];
    const float* W1  = (const float*)d_in[4];
    const float* b1  = (const float*)d_in[5];
    const float* W2  = (const float*)d_in[6];
    const float* b2  = (const float*)d_in[7];
    const float* Wp1 = (const float*)d_in[8];
    const float* bp1 = (const float*)d_in[9];
    const float* Wp2 = (const float*)d_in[10];
    const float* bp2 = (const float*)d_in[11];
    float* out = (float*)d_out;

    // workspace carve-up
    char* w = (char*)d_ws;
    size_t off = 0;
    ushort* Xc   = (ushort*)(w + off); off += (size_t)MPAD * 256 * 2;   // 25.6 MB
    ushort* Pn   = (ushort*)(w + off); off += (size_t)MPAD * 512 * 2;   // 51.2 MB
    ushort* WcT  = (ushort*)(w + off); off += 512 * 256 * 2;
    ushort* W2t  = (ushort*)(w + off); off += 32768;
    ushort* Wp2t = (ushort*)(w + off); off += 32768;
    float*  w1d  = (float*)(w + off);  off += 2048;
    float*  wp1d = (float*)(w + off);  off += 2048;
    int* cnt     = (int*)(w + off);    off += 200704;                   // 50176*4
    int* startA  = (int*)(w + off);    off += 200704;
    int* cursor  = (int*)(w + off);    off += 200704;
    int* locs    = (int*)(w + off);    off += 200704;
    int* sums    = (int*)(w + off);    off += 512;
    int* sendS   = (int*)(w + off);    off += (size_t)NE * 4;
    int* recS    = (int*)(w + off);    off += (size_t)NE * 4;
    float* distS = (float*)(w + off);  off += (size_t)NE * 4;
    uint32_t* tileSegs = (uint32_t*)(w + off); off += (size_t)NTILE * 128 * 4;  // 1.6 MB
    int* segCntA = (int*)(w + off);    off += (size_t)NTILE * 4;
    int* nodeCov = (int*)(w + off);    off += 200704;

    // sort edges by receiver (+ dist/send/rec extraction)
    hipMemsetAsync(cnt, 0, (N_NODES + 1) * sizeof(int), stream);
    k_hist<<<(NE + 255) / 256, 256, 0, stream>>>(eidx, cnt);
    k_scan1<<<SCAN_NB, SCAN_BS, 0, stream>>>(cnt, locs, sums);
    k_scan2<<<1, 128, 0, stream>>>(sums);
    k_scan3<<<SCAN_NB, SCAN_BS, 0, stream>>>(cnt, locs, sums, startA, cursor, nodeCov);
    k_place<<<(NE + 255) / 256, 256, 0, stream>>>(eidx, pos, cursor, sendS, recS, distS);
    k_segmeta<<<NTILE, 128, 0, stream>>>(recS, startA, cnt, tileSegs, segCntA);

    // prep (fused Xc build + out baseline init for non-covered nodes only)
    k_prep_w<<<769, 256, 0, stream>>>(W1, Wp1, W2, Wp2, WcT, W2t, Wp2t, w1d, wp1d);
    k_prep_nodes<<<MPAD / 4, 256, 0, stream>>>((const float4*)x, (const float4*)pe,
                                               nodeCov, Xc, (float4*)out);

    // node-level GEMM: Pn = Xc @ Wc
    dim3 ggrid(4, MPAD / 128);
    k_node_gemm<<<ggrid, 256, 0, stream>>>(Xc, WcT, Pn);

    // fused edge pipeline: gather + layer1 + layer2 + segment reduce, both p paths
    dim3 fgrid(NTILE, 2);
    k_fused<<<fgrid, 256, 0, stream>>>(Pn, sendS, recS, distS, tileSegs, segCntA,
                                       w1d, wp1d, b1, bp1, W2t, Wp2t, b2, bp2,
                                       x, pe, out);
}

// Round 7
// 378.253 us; speedup vs baseline: 1.2585x; 1.0134x over previous
//
#include <hip/hip_runtime.h>
#include <stdint.h>

// Problem constants (from reference setup_inputs)
#define N_NODES 50000
#define NE      400000
#define HDIM    128
#define MPAD    50048     // 391 * 128, zero-padded rows for clean GEMM tiling
#define TE      128       // edges per tile in fused kernel
#define NTILE   (NE / TE) // 3125 (exact: 400000 = 3125*128)
#define SCAN_BS 512
#define SCAN_NB 98        // 98*512 = 50176 >= 50001

typedef __attribute__((ext_vector_type(8))) short bf16x8;   // 8 bf16 in 4 VGPRs
typedef __attribute__((ext_vector_type(4))) float f32x4;

// f32 -> bf16, RTNE via bit ops (prep/cold paths). DO NOT use (__bf16) casts:
// rounds 2+3 showed that path lowers through a libcall that spills all live
// regs around each call (WRITE_SIZE 58 MB -> 433/1019 MB).
__device__ __forceinline__ ushort f2b(float f) {
    uint32_t u = __float_as_uint(f);
    uint32_t r = (u + 0x7fffu + ((u >> 16) & 1u)) >> 16;   // RTNE
    return (ushort)r;
}
__device__ __forceinline__ float b2f(ushort s) {
    return __uint_as_float(((uint32_t)s) << 16);
}
// hot-path pair convert: single v_cvt_pk_bf16_f32 (RTNE), inline asm
// (real gfx950 instruction; avoids the libcall the (__bf16) cast takes).
__device__ __forceinline__ uint32_t cvtpk(float lo, float hi) {
    uint32_t r;
    asm("v_cvt_pk_bf16_f32 %0, %1, %2" : "=v"(r) : "v"(lo), "v"(hi));
    return r;
}

// activations: approx rcp instead of precise f32 division (saves ~9 VALU/elem)
__device__ __forceinline__ float silu_f(float x) {
    return x * __builtin_amdgcn_rcpf(1.f + __expf(-x));
}
__device__ __forceinline__ float tanh_f(float x) {
    return fmaf(-2.f, __builtin_amdgcn_rcpf(1.f + __expf(2.f * x)), 1.f);
}

// ---------------------------------------------------------------------------
// Merged prep: blocks [0,769) build transposed weights; blocks [769, ...)
// build Xc (bf16 x|pe) + out baseline for non-covered nodes.
__global__ void k_prep(const float* __restrict__ W1, const float* __restrict__ Wp1,
                       const float* __restrict__ W2, const float* __restrict__ Wp2,
                       ushort* __restrict__ WcT, ushort* __restrict__ W2t,
                       ushort* __restrict__ Wp2t, float* __restrict__ w1d,
                       float* __restrict__ wp1d,
                       const float4* __restrict__ x, const float4* __restrict__ pe,
                       const int* __restrict__ cov,
                       ushort* __restrict__ Xc, float4* __restrict__ out) {
    int b = blockIdx.x, t = threadIdx.x;
    if (b < 769) {
        if (b < 512) {
            int n = b, k = t;
            float v;
            if (n < 128)       v = W1[k * HDIM + n];
            else if (n < 256)  v = W1[(256 + k) * HDIM + (n - 128)];
            else if (n < 384)  v = (k < 128) ? 0.f : Wp1[(k - 128) * HDIM + (n - 256)];
            else               v = (k < 128) ? 0.f : Wp1[k * HDIM + (n - 384)];
            WcT[n * 256 + k] = f2b(v);
        } else if (b < 640) {
            if (t < 128) { int n = b - 512; W2t[n * HDIM + t] = f2b(W2[t * HDIM + n]); }
        } else if (b < 768) {
            if (t < 128) { int n = b - 640; Wp2t[n * HDIM + t] = f2b(Wp2[t * HDIM + n]); }
        } else {
            if (t < 128) w1d[t] = W1[512 * HDIM + t];
            else if (t < 256) wp1d[t - 128] = Wp1[256 * HDIM + (t - 128)];
        }
        return;
    }
    int idx = (b - 769) * 256 + t;
    int row = idx >> 6;
    int cq  = idx & 63;
    float4 v = make_float4(0.f, 0.f, 0.f, 0.f);
    if (row < N_NODES) {
        bool wr = (cov[row] == 0);
        if (cq < 32) { v = x[row * 32 + cq];          if (wr) out[row * 32 + cq] = v; }
        else         { v = pe[row * 32 + (cq - 32)];  if (wr) out[N_NODES * 32 + row * 32 + (cq - 32)] = v; }
    }
    ushort r[4] = { f2b(v.x), f2b(v.y), f2b(v.z), f2b(v.w) };
    *(uint2*)(Xc + (size_t)row * 256 + cq * 4) = *(const uint2*)r;
}

// ---------------------------------------------------------------------------
// Counting sort by receiver: hist -> 3-kernel multi-block scan -> place(+dist).
__global__ void k_hist(const int* __restrict__ eidx, int* __restrict__ cnt) {
    int e = blockIdx.x * 256 + threadIdx.x;
    if (e < NE) atomicAdd(&cnt[eidx[NE + e]], 1);
}

__global__ __launch_bounds__(SCAN_BS) void k_scan1(const int* __restrict__ cnt,
                                                   int* __restrict__ locs,
                                                   int* __restrict__ sums) {
    __shared__ int sh[SCAN_BS];
    int tid = threadIdx.x;
    int i = blockIdx.x * SCAN_BS + tid;
    int v = (i < N_NODES) ? cnt[i] : 0;
    sh[tid] = v;
    __syncthreads();
    for (int off = 1; off < SCAN_BS; off <<= 1) {
        int t = (tid >= off) ? sh[tid - off] : 0;
        __syncthreads();
        sh[tid] += t;
        __syncthreads();
    }
    locs[i] = sh[tid];                       // inclusive scan within block
    if (tid == SCAN_BS - 1) sums[blockIdx.x] = sh[tid];
}

__global__ void k_scan2(int* __restrict__ sums) {
    __shared__ int sh[128];
    int tid = threadIdx.x;
    sh[tid] = (tid < SCAN_NB) ? sums[tid] : 0;
    __syncthreads();
    for (int off = 1; off < 128; off <<= 1) {
        int t = (tid >= off) ? sh[tid - off] : 0;
        __syncthreads();
        sh[tid] += t;
        __syncthreads();
    }
    if (tid < SCAN_NB) sums[tid] = sh[tid];  // inclusive block sums
}

__global__ __launch_bounds__(SCAN_BS) void k_scan3(const int* __restrict__ cnt,
                                                   const int* __restrict__ locs,
                                                   const int* __restrict__ sums,
                                                   int* __restrict__ start,
                                                   int* __restrict__ cursor,
                                                   int* __restrict__ nodeCov) {
    int tid = threadIdx.x, b = blockIdx.x;
    int i = b * SCAN_BS + tid;
    if (i > N_NODES) return;
    int base = b ? sums[b - 1] : 0;
    int v = (i < N_NODES) ? cnt[i] : 0;
    int ex = base + locs[i] - v;             // exclusive prefix
    start[i] = ex;
    if (i < N_NODES) {
        cursor[i] = ex;
        int covered = (v > 0) && ((ex >> 7) == ((ex + v - 1) >> 7));
        nodeCov[i] = covered;
    }
}

// place edge into sorted slot; also extract send/rec/dist into sorted arrays
__global__ void k_place(const int* __restrict__ eidx, const float* __restrict__ pos,
                        int* __restrict__ cursor, int* __restrict__ sendS,
                        int* __restrict__ recS, float* __restrict__ distS) {
    int e = blockIdx.x * 256 + threadIdx.x;
    if (e >= NE) return;
    int s = eidx[e], r = eidx[NE + e];
    int p = atomicAdd(&cursor[r], 1);
    sendS[p] = s; recS[p] = r;
    float dx = pos[s * 3 + 0] - pos[r * 3 + 0];
    float dy = pos[s * 3 + 1] - pos[r * 3 + 1];
    float dz = pos[s * 3 + 2] - pos[r * 3 + 2];
    distS[p] = sqrtf(dx * dx + dy * dy + dz * dz);
}

// ---------------------------------------------------------------------------
// Per-tile segment metadata, computed ONCE (p-invariant). Ballot/popcount
// flag-scan: 1 barrier instead of ~16 (round-7 rewrite, output identical).
//   word = r0 | (len-1)<<7 | interior<<14 | node<<16
__global__ __launch_bounds__(128) void k_segmeta(const int* __restrict__ recS,
                                                 const int* __restrict__ startA,
                                                 const int* __restrict__ cntA,
                                                 uint32_t* __restrict__ tileSegs,
                                                 int* __restrict__ segCnt) {
    __shared__ unsigned long long sMask[2];
    int tid = threadIdx.x;
    int t0 = blockIdx.x * 128;
    int r = recS[t0 + tid];
    int f = (tid == 0) ? 1 : (r != recS[t0 + tid - 1]);
    int wv = tid >> 6, lane = tid & 63;
    unsigned long long m = __ballot(f);
    if (lane == 0) sMask[wv] = m;
    __syncthreads();
    unsigned long long m0 = sMask[0], m1 = sMask[1];
    int total0 = __popcll(m0);
    if (tid == 0) segCnt[blockIdx.x] = total0 + __popcll(m1);
    if (f) {
        unsigned long long below = m & ((1ull << lane) - 1ull);
        int seg = __popcll(below) + (wv ? total0 : 0);
        unsigned long long higher = (lane == 63) ? 0ull : (m >> (lane + 1));
        int next;
        if (higher)       next = tid + 1 + __builtin_ctzll(higher);
        else if (wv == 0) next = m1 ? 64 + __builtin_ctzll(m1) : 128;
        else              next = 128;
        int len = next - tid;
        int g0 = t0 + tid;
        int st = startA[r];
        uint32_t interior = (g0 == st) && (g0 + len == st + cntA[r]);
        tileSegs[(size_t)blockIdx.x * 128 + seg] =
            (uint32_t)tid | ((uint32_t)(len - 1) << 7) | (interior << 14) | ((uint32_t)r << 16);
    }
}

// ---------------------------------------------------------------------------
// Pn[MPAD,512] bf16 = Xc[MPAD,256] @ Wc[256,512], via WcT.
// 1D grid of 1564 blocks with bijective chunked XCD swizzle (1564 = 8*195+4):
// the 4 n-blocks sharing an A-tile (m0) become consecutive on ONE XCD, so the
// 64 KB Xc tile is fetched from HBM once and L2-hits 3 times.
__global__ __launch_bounds__(256) void k_node_gemm(const ushort* __restrict__ Xc,
                                                   const ushort* __restrict__ WcT,
                                                   ushort* __restrict__ Pn) {
    const int bid = blockIdx.x;                 // 0..1563
    const int q = 195, r4 = 4;                  // 1564 = 8*q + r4
    const int xcd = bid & 7, j = bid >> 3;
    const int orig = (xcd < r4 ? xcd * (q + 1) : r4 * (q + 1) + (xcd - r4) * q) + j;
    const int m0 = (orig >> 2) * 128;
    const int n0 = (orig & 3) * 128;
    const int wave = threadIdx.x >> 6;
    const int lane = threadIdx.x & 63;
    const int l15 = lane & 15, quad = lane >> 4;
    const int qr = (wave >> 1) * 64, qc = (wave & 1) * 64;

    f32x4 acc[4][4];
#pragma unroll
    for (int i = 0; i < 4; i++)
#pragma unroll
        for (int jj = 0; jj < 4; jj++) acc[i][jj] = (f32x4){0.f, 0.f, 0.f, 0.f};

#pragma unroll
    for (int s = 0; s < 8; s++) {
        const int k0 = s * 32 + quad * 8;
        bf16x8 a[4], b[4];
#pragma unroll
        for (int rg = 0; rg < 4; rg++) {
            int row = m0 + qr + rg * 16 + l15;
            a[rg] = *(const bf16x8*)(Xc + row * 256 + k0);
        }
#pragma unroll
        for (int cg = 0; cg < 4; cg++) {
            int nn = n0 + qc + cg * 16 + l15;
            b[cg] = *(const bf16x8*)(WcT + nn * 256 + k0);
        }
#pragma unroll
        for (int rg = 0; rg < 4; rg++)
#pragma unroll
            for (int cg = 0; cg < 4; cg++)
                acc[rg][cg] = __builtin_amdgcn_mfma_f32_16x16x32_bf16(a[rg], b[cg], acc[rg][cg], 0, 0, 0);
    }

#pragma unroll
    for (int rg = 0; rg < 4; rg++)
#pragma unroll
        for (int cg = 0; cg < 4; cg++) {
            int col = n0 + qc + cg * 16 + l15;
            int rowb = m0 + qr + rg * 16 + quad * 4;
            uint32_t p01 = cvtpk(acc[rg][cg][0], acc[rg][cg][1]);
            uint32_t p23 = cvtpk(acc[rg][cg][2], acc[rg][cg][3]);
            Pn[(size_t)(rowb + 0) * 512 + col] = (ushort)p01;
            Pn[(size_t)(rowb + 1) * 512 + col] = (ushort)(p01 >> 16);
            Pn[(size_t)(rowb + 2) * 512 + col] = (ushort)p23;
            Pn[(size_t)(rowb + 3) * 512 + col] = (ushort)(p23 >> 16);
        }
}

// ---------------------------------------------------------------------------
// FUSED edge pipeline (UNCHANGED from round-6 verified 154 us version).
__global__ __launch_bounds__(256, 4) void k_fused(
    const ushort* __restrict__ Pn,
    const int* __restrict__ sendS, const int* __restrict__ recS,
    const float* __restrict__ distS,
    const uint32_t* __restrict__ tileSegs, const int* __restrict__ segCntA,
    const float* __restrict__ w1d, const float* __restrict__ wp1d,
    const float* __restrict__ b1, const float* __restrict__ bp1,
    const ushort* __restrict__ W2t, const ushort* __restrict__ Wp2t,
    const float* __restrict__ b2, const float* __restrict__ bp2,
    const float* __restrict__ x, const float* __restrict__ pe,
    float* __restrict__ out)
{
    __shared__ __align__(16) ushort sA[TE * 128];   // h1 tile (swizzled), then msg tile
    __shared__ int sS[TE];
    __shared__ int sR[TE];
    __shared__ float sD[TE];
    __shared__ uint32_t sSeg[TE];

    const int tid = threadIdx.x;
    const int tile = blockIdx.x;
    const int p = blockIdx.y;
    const int t0 = tile * TE;

    // phase 0: stage sorted-edge meta + precomputed segments
    if (tid < TE) {
        sS[tid] = sendS[t0 + tid];
        sR[tid] = recS[t0 + tid];
        sD[tid] = distS[t0 + tid];
    } else {
        sSeg[tid - TE] = tileSegs[(size_t)tile * TE + (tid - TE)];
    }
    const int nSeg = segCntA[tile];

    const int g = tid >> 4, c = tid & 15;       // 16 col-groups x 16 threads; 8 edges/thread
    const float* wd = p ? wp1d : w1d;
    const float* bb = p ? bp1 : b1;
    float4 wv0 = *(const float4*)(wd + c * 8);
    float4 wv1 = *(const float4*)(wd + c * 8 + 4);
    float4 bv0 = *(const float4*)(bb + c * 8);
    float4 bv1 = *(const float4*)(bb + c * 8 + 4);
    float wva[8] = { wv0.x, wv0.y, wv0.z, wv0.w, wv1.x, wv1.y, wv1.z, wv1.w };
    float bva[8] = { bv0.x, bv0.y, bv0.z, bv0.w, bv1.x, bv1.y, bv1.z, bv1.w };
    __syncthreads();

    // phase 1: register gather from Pn (16 independent 16B loads) + layer-1
    {
        const ushort* PnS = Pn + p * 256 + c * 8;         // send-part cols
        const ushort* PnR = Pn + p * 256 + 128 + c * 8;   // rec-part cols
        uint4 us[8], ur[8];
#pragma unroll
        for (int e = 0; e < 8; e++) {
            int el = g * 8 + e;
            us[e] = *(const uint4*)(PnS + (size_t)sS[el] * 512);
            ur[e] = *(const uint4*)(PnR + (size_t)sR[el] * 512);
        }
#define L1_BODY(ACT)                                                        \
        for (int e = 0; e < 8; e++) {                                       \
            int el = g * 8 + e;                                             \
            float d = sD[el];                                               \
            const ushort* pus = (const ushort*)&us[e];                      \
            const ushort* pur = (const ushort*)&ur[e];                      \
            float vv[8];                                                    \
            _Pragma("unroll")                                               \
            for (int j = 0; j < 8; j++) {                                   \
                float v = b2f(pus[j]) + b2f(pur[j]) + d * wva[j] + bva[j];  \
                vv[j] = ACT(v);                                             \
            }                                                               \
            uint4 res;                                                      \
            res.x = cvtpk(vv[0], vv[1]);                                    \
            res.y = cvtpk(vv[2], vv[3]);                                    \
            res.z = cvtpk(vv[4], vv[5]);                                    \
            res.w = cvtpk(vv[6], vv[7]);                                    \
            *(uint4*)(sA + el * 128 + ((c ^ (el & 15)) * 8)) = res;         \
        }
        if (p) {
#pragma unroll
            L1_BODY(tanh_f)
        } else {
#pragma unroll
            L1_BODY(silu_f)
        }
#undef L1_BODY
    }
    __syncthreads();

    // phase 2: layer-2 MFMA; A from swizzled sA, B from global (L1-resident 32 KB)
    const int wave = tid >> 6, lane = tid & 63;
    const int l15 = lane & 15, quad = lane >> 4;
    const ushort* Wt = p ? Wp2t : W2t;

    f32x4 acc[2][8];
#pragma unroll
    for (int rg = 0; rg < 2; rg++)
#pragma unroll
        for (int cg = 0; cg < 8; cg++) acc[rg][cg] = (f32x4){0.f, 0.f, 0.f, 0.f};

#pragma unroll
    for (int s4 = 0; s4 < 4; s4++) {
        int cidx = s4 * 4 + quad;
        int row0 = wave * 32 + l15;                 // row & 15 == l15
        bf16x8 a0 = *(const bf16x8*)(sA + row0 * 128 + ((cidx ^ l15) * 8));
        bf16x8 a1 = *(const bf16x8*)(sA + (row0 + 16) * 128 + ((cidx ^ l15) * 8));
        int k0 = cidx * 8;
#pragma unroll
        for (int cg = 0; cg < 8; cg++) {
            bf16x8 b = *(const bf16x8*)(Wt + (cg * 16 + l15) * HDIM + k0);
            acc[0][cg] = __builtin_amdgcn_mfma_f32_16x16x32_bf16(a0, b, acc[0][cg], 0, 0, 0);
            acc[1][cg] = __builtin_amdgcn_mfma_f32_16x16x32_bf16(a1, b, acc[1][cg], 0, 0, 0);
        }
    }
    __syncthreads();   // all h1 reads done before msg overwrite

    // phase 3: bias + activation, msg tile into sA (plain layout)
    const float* bb2 = p ? bp2 : b2;
#define EPI_BODY(ACT)                                                       \
    for (int rg = 0; rg < 2; rg++) {                                        \
        int rowb = wave * 32 + rg * 16 + quad * 4;                          \
        _Pragma("unroll")                                                   \
        for (int cg = 0; cg < 8; cg++) {                                    \
            int col = cg * 16 + l15;                                        \
            float bias = bb2[col];                                          \
            float e0 = ACT(acc[rg][cg][0] + bias);                          \
            float e1 = ACT(acc[rg][cg][1] + bias);                          \
            float e2 = ACT(acc[rg][cg][2] + bias);                          \
            float e3 = ACT(acc[rg][cg][3] + bias);                          \
            uint32_t p01 = cvtpk(e0, e1);                                   \
            uint32_t p23 = cvtpk(e2, e3);                                   \
            sA[(rowb + 0) * 128 + col] = (ushort)p01;                       \
            sA[(rowb + 1) * 128 + col] = (ushort)(p01 >> 16);               \
            sA[(rowb + 2) * 128 + col] = (ushort)p23;                       \
            sA[(rowb + 3) * 128 + col] = (ushort)(p23 >> 16);               \
        }                                                                   \
    }
    if (p) {
#pragma unroll
        EPI_BODY(tanh_f)
    } else {
#pragma unroll
        EPI_BODY(silu_f)
    }
#undef EPI_BODY
    __syncthreads();

    // phase 4: segment reduce + store/atomic using precomputed meta
    const float* basep = p ? pe : x;
    float* outb = out + (size_t)p * N_NODES * HDIM;
    for (int task = tid; task < nSeg * 64; task += 256) {
        int seg = task >> 6, cp = task & 63;
        uint32_t wseg = sSeg[seg];
        int r0  = wseg & 127;
        int len = ((wseg >> 7) & 127) + 1;
        int n   = wseg >> 16;
        float a0 = 0.f, a1 = 0.f;
        for (int rr = r0; rr < r0 + len; rr++) {
            unsigned int u = *(const unsigned int*)&sA[rr * 128 + cp * 2];
            a0 += b2f((ushort)(u & 0xffffu));
            a1 += b2f((ushort)(u >> 16));
        }
        float* op = outb + (size_t)n * HDIM + cp * 2;
        if ((wseg >> 14) & 1) {                     // interior: direct store
            float2 bv = *(const float2*)(basep + (size_t)n * HDIM + cp * 2);
            *(float2*)op = make_float2(bv.x + a0, bv.y + a1);
        } else {                                    // boundary: atomic
            atomicAdd(op, a0);
            atomicAdd(op + 1, a1);
        }
    }
}

// ---------------------------------------------------------------------------
extern "C" void kernel_launch(void* const* d_in, const int* in_sizes, int n_in,
                              void* d_out, int out_size, void* d_ws, size_t ws_size,
                              hipStream_t stream) {
    const float* x   = (const float*)d_in[0];
    const float* pos = (const float*)d_in[1];
    const float* pe  = (const float*)d_in[2];
    const int* eidx  = (const int*)d_in[3];
    const float* W1  = (const float*)d_in[4];
    const float* b1  = (const float*)d_in[5];
    const float* W2  = (const float*)d_in[6];
    const float* b2  = (const float*)d_in[7];
    const float* Wp1 = (const float*)d_in[8];
    const float* bp1 = (const float*)d_in[9];
    const float* Wp2 = (const float*)d_in[10];
    const float* bp2 = (const float*)d_in[11];
    float* out = (float*)d_out;

    // workspace carve-up
    char* w = (char*)d_ws;
    size_t off = 0;
    ushort* Xc   = (ushort*)(w + off); off += (size_t)MPAD * 256 * 2;   // 25.6 MB
    ushort* Pn   = (ushort*)(w + off); off += (size_t)MPAD * 512 * 2;   // 51.2 MB
    ushort* WcT  = (ushort*)(w + off); off += 512 * 256 * 2;
    ushort* W2t  = (ushort*)(w + off); off += 32768;
    ushort* Wp2t = (ushort*)(w + off); off += 32768;
    float*  w1d  = (float*)(w + off);  off += 2048;
    float*  wp1d = (float*)(w + off);  off += 2048;
    int* cnt     = (int*)(w + off);    off += 200704;                   // 50176*4
    int* startA  = (int*)(w + off);    off += 200704;
    int* cursor  = (int*)(w + off);    off += 200704;
    int* locs    = (int*)(w + off);    off += 200704;
    int* sums    = (int*)(w + off);    off += 512;
    int* sendS   = (int*)(w + off);    off += (size_t)NE * 4;
    int* recS    = (int*)(w + off);    off += (size_t)NE * 4;
    float* distS = (float*)(w + off);  off += (size_t)NE * 4;
    uint32_t* tileSegs = (uint32_t*)(w + off); off += (size_t)NTILE * 128 * 4;  // 1.6 MB
    int* segCntA = (int*)(w + off);    off += (size_t)NTILE * 4;
    int* nodeCov = (int*)(w + off);    off += 200704;

    // sort edges by receiver (+ dist/send/rec extraction)
    hipMemsetAsync(cnt, 0, (N_NODES + 1) * sizeof(int), stream);
    k_hist<<<(NE + 255) / 256, 256, 0, stream>>>(eidx, cnt);
    k_scan1<<<SCAN_NB, SCAN_BS, 0, stream>>>(cnt, locs, sums);
    k_scan2<<<1, 128, 0, stream>>>(sums);
    k_scan3<<<SCAN_NB, SCAN_BS, 0, stream>>>(cnt, locs, sums, startA, cursor, nodeCov);
    k_place<<<(NE + 255) / 256, 256, 0, stream>>>(eidx, pos, cursor, sendS, recS, distS);
    k_segmeta<<<NTILE, 128, 0, stream>>>(recS, startA, cnt, tileSegs, segCntA);

    // merged prep (weights + Xc build + out baseline for non-covered nodes)
    k_prep<<<769 + MPAD / 4, 256, 0, stream>>>(W1, Wp1, W2, Wp2, WcT, W2t, Wp2t,
                                               w1d, wp1d, (const float4*)x,
                                               (const float4*)pe, nodeCov, Xc,
                                               (float4*)out);

    // node-level GEMM: Pn = Xc @ Wc (1D grid, XCD-swizzled for A-tile L2 reuse)
    k_node_gemm<<<1564, 256, 0, stream>>>(Xc, WcT, Pn);

    // fused edge pipeline: gather + layer1 + layer2 + segment reduce, both p paths
    dim3 fgrid(NTILE, 2);
    k_fused<<<fgrid, 256, 0, stream>>>(Pn, sendS, recS, distS, tileSegs, segCntA,
                                       w1d, wp1d, b1, bp1, W2t, Wp2t, b2, bp2,
                                       x, pe, out);
}